// Round 4
// baseline (196.726 us; speedup 1.0000x reference)
//
#include <hip/hip_runtime.h>

#define SEQ  2048
#define RDIM 384
#define CDIM 64

typedef __attribute__((ext_vector_type(8))) short s16x8;
typedef __attribute__((ext_vector_type(4))) float f32x4;
#define MFMA(a,b,c) __builtin_amdgcn_mfma_f32_16x16x32_bf16(a,b,c,0,0,0)

__device__ __forceinline__ unsigned short f2bf(float x) {
    union { float f; unsigned u; } a; a.f = x;
    unsigned r = a.u + 0x7fffu + ((a.u >> 16) & 1u);
    return (unsigned short)(r >> 16);
}
__device__ __forceinline__ unsigned pack2(float lo, float hi) {
    return (unsigned)f2bf(lo) | ((unsigned)f2bf(hi) << 16);
}
__device__ __forceinline__ float bf2f(unsigned u16) {
    union { unsigned u; float f; } a; a.u = u16 << 16; return a.f;
}

// element offset of (row, k) in a [rows][64] bf16 tile, 8-elem-group XOR swizzle
#define SWZ(row,k) ((row)*64 + (((((k)>>3) ^ ((row)&7)))<<3) + ((k)&7))

#define KVS_STRIDE 1032   // 1024 data shorts + 8 pad: 2064 B, 16B-aligned, 4-dw bank skew

// ---------------- prep: LN-folded transposed/permuted bf16 weights ----------------
__global__ __launch_bounds__(256) void k_prep(
    const float* __restrict__ Wk, const float* __restrict__ Wv,
    const float* __restrict__ Wg, const float* __restrict__ Wf,
    const float* __restrict__ lnw, const float* __restrict__ lnb,
    const float* __restrict__ bg,
    unsigned short* __restrict__ wkvt, unsigned short* __restrict__ wgt,
    unsigned short* __restrict__ wfp, float* __restrict__ kvbias,
    float* __restrict__ bgp)
{
    const int t = threadIdx.x, b = blockIdx.x;
    if (b == 0) {
        for (int idx = t; idx < 16 * 64; idx += 256) {
            const int kc = idx >> 6, k = idx & 63;
            const float v = lnw[k] * ((kc < 8) ? Wk[k * 8 + kc] : Wv[k * 8 + (kc - 8)]);
            wkvt[SWZ(kc, k)] = f2bf(v);
        }
        if (t < 16) {
            float a = 0.f;
            for (int k = 0; k < 64; k++)
                a += lnb[k] * ((t < 8) ? Wk[k * 8 + t] : Wv[k * 8 + (t - 8)]);
            kvbias[t] = a;
        }
    } else if (b == 1) {
        for (int idx = t; idx < 64 * 64; idx += 256) {
            const int col = idx >> 6, k = idx & 63;
            wgt[SWZ(col, k)] = f2bf(lnw[k] * Wg[k * 64 + col]);
        }
        if (t < 64) {
            float a = bg[t];
            for (int k = 0; k < 64; k++) a += lnb[k] * Wg[k * 64 + t];
            bgp[t] = a;
        }
    } else {
        for (int idx = t; idx < 64 * 64; idx += 256) {
            const int cout = idx >> 6, p = idx & 63;
            const int kst = p >> 5, h = (p >> 3) & 3, rr = p & 7;
            const int j = kst * 32 + (rr < 4 ? 4 * h + rr : 16 + 4 * h + (rr - 4));
            wfp[SWZ(cout, p)] = f2bf(Wf[j * 64 + cout]);
        }
    }
}

// ---------------- Phase 1: LN(xhat) + q_avg partials + kv projection (MFMA) ----------------
__global__ __launch_bounds__(256) void k_phase1(
    const float* __restrict__ x, const unsigned short* __restrict__ wkvt,
    float* __restrict__ qpart, unsigned short* __restrict__ kv)
{
    __shared__ __align__(16) unsigned short xs[128 * 64];          // swizzled bf16 xhat sub-tile
    __shared__ __align__(16) unsigned short wkv[16 * 64];          // pre-swizzled LN-folded Wkv^T
    __shared__ __align__(16) unsigned short kvs[16 * KVS_STRIDE];  // kv tile staging (coalesced dump)
    const int t = threadIdx.x;
    ((unsigned*)wkv)[t]       = ((const unsigned*)wkvt)[t];
    ((unsigned*)wkv)[t + 256] = ((const unsigned*)wkvt)[t + 256];

    const int rtile  = blockIdx.x % 24;
    const int schunk = blockIdx.x / 24;
    const int g  = t >> 4;      // row group (fixed r)
    const int c4 = t & 15;      // float4 column
    const int r = rtile * 16 + g;
    const int wv = t >> 6, lane = t & 63, hi = lane >> 4, l15 = lane & 15;

    float qs0 = 0.f, qs1 = 0.f, qs2 = 0.f, qs3 = 0.f;
    for (int sub = 0; sub < 8; ++sub) {
        __syncthreads();   // xs free (iter0: wkv staged)
        #pragma unroll
        for (int it = 0; it < 8; ++it) {
            const int row = it * 16 + g;
            const int s = schunk * 64 + sub * 8 + it;
            const float4 xv = *(const float4*)(x + ((size_t)s * RDIM + r) * CDIM + (c4 << 2));
            float sum = xv.x + xv.y + xv.z + xv.w;
            float sq  = xv.x * xv.x + xv.y * xv.y + xv.z * xv.z + xv.w * xv.w;
            #pragma unroll
            for (int m = 1; m < 16; m <<= 1) {
                sum += __shfl_xor(sum, m, 16);
                sq  += __shfl_xor(sq,  m, 16);
            }
            const float mu   = sum * (1.0f / 64.0f);
            const float rstd = rsqrtf(sq * (1.0f / 64.0f) - mu * mu + 1e-5f);
            const float xn0 = (xv.x - mu) * rstd;
            const float xn1 = (xv.y - mu) * rstd;
            const float xn2 = (xv.z - mu) * rstd;
            const float xn3 = (xv.w - mu) * rstd;
            qs0 += xn0; qs1 += xn1; qs2 += xn2; qs3 += xn3;
            ushort4 pk; pk.x = f2bf(xn0); pk.y = f2bf(xn1); pk.z = f2bf(xn2); pk.w = f2bf(xn3);
            *(ushort4*)&xs[row * 64 + ((((c4 >> 1) ^ (row & 7)) << 3) | ((c4 & 1) << 2))] = pk;
        }
        __syncthreads();
        // kv^T = Wkv'^T @ xhat^T : per wave 32 rows, 4 MFMA -> stage into kvs LDS
        f32x4 acc0 = 0, acc1 = 0;
        #pragma unroll
        for (int kst = 0; kst < 2; ++kst) {
            const int kg = (kst * 4 + hi);
            const s16x8 a = *(const s16x8*)&wkv[l15 * 64 + ((kg ^ (l15 & 7)) << 3)];
            const int row0 = wv * 32 + l15;
            const s16x8 b0 = *(const s16x8*)&xs[row0 * 64 + ((kg ^ (l15 & 7)) << 3)];
            const s16x8 b1 = *(const s16x8*)&xs[(row0 + 16) * 64 + ((kg ^ (l15 & 7)) << 3)];
            acc0 = MFMA(a, b0, acc0);
            acc1 = MFMA(a, b1, acc1);
        }
        #pragma unroll
        for (int ni = 0; ni < 2; ++ni) {
            const f32x4 av = ni ? acc1 : acc0;
            const int sloc = sub * 8 + 2 * wv + ni;           // 0..63
            ushort4 pk; pk.x = f2bf(av[0]); pk.y = f2bf(av[1]); pk.z = f2bf(av[2]); pk.w = f2bf(av[3]);
            *(ushort4*)&kvs[l15 * KVS_STRIDE + sloc * 16 + (hi << 2)] = pk;
        }
    }
    float4 q4; q4.x = qs0; q4.y = qs1; q4.z = qs2; q4.w = qs3;
    *(float4*)(qpart + ((size_t)schunk * RDIM + r) * CDIM + (c4 << 2)) = q4;

    // coalesced kv dump: per r-row 2 KB contiguous, lane-interleaved uint4s
    __syncthreads();
    {
        const int rr = t >> 4, seg = t & 15;
        uint4* dstq = (uint4*)(kv + (size_t)(rtile * 16 + rr) * (SEQ * 16) + (size_t)schunk * 1024);
        #pragma unroll
        for (int i = 0; i < 8; ++i)
            dstq[seg + 16 * i] = *(const uint4*)&kvs[rr * KVS_STRIDE + (seg + 16 * i) * 8];
    }
}

// ---------------- Phase 2a: q + logits(no-max) + partial den/num per s-half ----------------
__global__ __launch_bounds__(256) void k_phase2a(
    const float* __restrict__ qpart, const float* __restrict__ Wq,
    const float* __restrict__ lnw, const float* __restrict__ lnb,
    const float* __restrict__ kvbias, const unsigned short* __restrict__ kv,
    float* __restrict__ num, float* __restrict__ den)
{
    __shared__ float qa[64];
    __shared__ float ql[64];
    __shared__ float lbias[8];
    __shared__ float hredd[4][8];
    __shared__ float wred[4][64];
    const int t = threadIdx.x;
    const int r = blockIdx.x >> 1;
    const int half = blockIdx.x & 1;
    if (t < 64) {
        float ssum = 0.f;
        #pragma unroll
        for (int ch = 0; ch < 32; ch++) ssum += qpart[(size_t)ch * (RDIM * CDIM) + r * 64 + t];
        qa[t] = ssum;
    }
    __syncthreads();
    if (t < 64) {
        float a = 0.f;
        for (int i = 0; i < 64; i++)
            a += (qa[i] * (1.0f / 2048.0f) * lnw[i] + lnb[i]) * Wq[i * 64 + t];
        ql[t] = a * 0.35355339059327373f;
    }
    __syncthreads();
    if (t < 8) {
        float a = 0.f;
        #pragma unroll
        for (int c = 0; c < 8; c++) a += ql[t * 8 + c] * kvbias[c];
        lbias[t] = a;
    }
    __syncthreads();

    const unsigned short* kvr = kv + (size_t)r * (SEQ * 16);
    float acc[64];
    float pd[8];
    #pragma unroll
    for (int j = 0; j < 64; j++) acc[j] = 0.f;
    #pragma unroll
    for (int h = 0; h < 8; h++) pd[h] = 0.f;

    #pragma unroll
    for (int i = 0; i < 4; i++) {
        const int s = half * 1024 + i * 256 + t;
        const uint4 ku = *(const uint4*)(kvr + (size_t)s * 16);
        const uint4 vu = *(const uint4*)(kvr + (size_t)s * 16 + 8);
        float kf[8], vf[8];
        kf[0] = bf2f(ku.x & 0xffff); kf[1] = bf2f(ku.x >> 16);
        kf[2] = bf2f(ku.y & 0xffff); kf[3] = bf2f(ku.y >> 16);
        kf[4] = bf2f(ku.z & 0xffff); kf[5] = bf2f(ku.z >> 16);
        kf[6] = bf2f(ku.w & 0xffff); kf[7] = bf2f(ku.w >> 16);
        vf[0] = bf2f(vu.x & 0xffff); vf[1] = bf2f(vu.x >> 16);
        vf[2] = bf2f(vu.y & 0xffff); vf[3] = bf2f(vu.y >> 16);
        vf[4] = bf2f(vu.z & 0xffff); vf[5] = bf2f(vu.z >> 16);
        vf[6] = bf2f(vu.w & 0xffff); vf[7] = bf2f(vu.w >> 16);
        #pragma unroll
        for (int h = 0; h < 8; h++) {
            float a = lbias[h];
            #pragma unroll
            for (int c = 0; c < 8; c++) a += ql[h * 8 + c] * kf[c];
            const float e = __expf(a);   // |logit| << 1, no max needed
            pd[h] += e;
            #pragma unroll
            for (int c = 0; c < 8; c++) acc[h * 8 + c] += e * vf[c];
        }
    }
    #pragma unroll
    for (int m = 1; m < 64; m <<= 1) {
        #pragma unroll
        for (int j = 0; j < 64; j++) acc[j] += __shfl_xor(acc[j], m, 64);
        #pragma unroll
        for (int h = 0; h < 8; h++) pd[h] += __shfl_xor(pd[h], m, 64);
    }
    const int wvi = t >> 6, lane = t & 63;
    if (lane == 0) {
        #pragma unroll
        for (int j = 0; j < 64; j++) wred[wvi][j] = acc[j];
        #pragma unroll
        for (int h = 0; h < 8; h++) hredd[wvi][h] = pd[h];
    }
    __syncthreads();
    if (t < 64)
        num[(size_t)(half * RDIM + r) * 64 + t] = wred[0][t] + wred[1][t] + wred[2][t] + wred[3][t];
    if (t < 8)
        den[(size_t)(half * RDIM + r) * 8 + t] = hredd[0][t] + hredd[1][t] + hredd[2][t] + hredd[3][t];
}

// ---------------- Phase 2b: merge halves + pack o into phase3 fragment image (f32) ----------------
__global__ __launch_bounds__(256) void k_phase2b(
    const float* __restrict__ num, const float* __restrict__ den,
    const float* __restrict__ kvbias, float* __restrict__ ofimg)
{
    const int idx = blockIdx.x * 256 + threadIdx.x;   // 0..24575
    const int r = idx >> 6, c = idx & 63;
    const float n = num[idx] + num[RDIM * 64 + idx];
    const float d = den[r * 8 + (c >> 3)] + den[(RDIM + r) * 8 + (c >> 3)];
    const float o = n / d + kvbias[8 + (c & 7)];
    const int rt = r >> 7, row = r & 127;
    const int wv = row >> 5, ni = (row >> 4) & 1, l15 = row & 15;
    const int mi = c >> 4, hi = (c >> 2) & 3, rg = c & 3;
    const int tt = wv * 64 + hi * 16 + l15;
    const int slot = ni * 16 + mi * 4 + rg;
    ofimg[((rt * 256 + tt) << 5) + slot] = o;
}

// ---------------- Phase 3: LN + gate GEMM -> reg epilogue -> out GEMM (pipelined) ----------------
__global__ __launch_bounds__(256, 3) void k_phase3(
    const float* __restrict__ x,
    const unsigned short* __restrict__ wgt, const unsigned short* __restrict__ wfp,
    const float* __restrict__ bgp, const float* __restrict__ bf_,
    const float* __restrict__ ofimg, float* __restrict__ out)
{
    __shared__ __align__(16) unsigned short xs[2][128 * 64];  // dbuf swizzled bf16 xhat
    __shared__ __align__(16) unsigned short wg[64 * 64];      // pre-swizzled LN-folded Wg^T
    __shared__ __align__(16) unsigned short wf[64 * 64];      // pre-swizzled+permuted Wf
    const int t = threadIdx.x;
    const int rt = blockIdx.x % 3;
    const int sb = blockIdx.x / 3;
    const int rbase = rt * 128;

    #pragma unroll
    for (int i = 0; i < 8; ++i) ((unsigned*)wg)[t + i * 256] = ((const unsigned*)wgt)[t + i * 256];
    #pragma unroll
    for (int i = 0; i < 8; ++i) ((unsigned*)wf)[t + i * 256] = ((const unsigned*)wfp)[t + i * 256];

    const int wv = t >> 6, lane = t & 63, hi = lane >> 4, l15 = lane & 15;

    float of32[32];   // o fragment values, f32
    {
        const float* osrc = ofimg + (size_t)(rt * 256 + t) * 32;
        #pragma unroll
        for (int i = 0; i < 8; ++i) *(float4*)&of32[i * 4] = *(const float4*)(osrc + i * 4);
    }
    float bgf[4][4], bff[4][4];
    #pragma unroll
    for (int mi = 0; mi < 4; ++mi) *(float4*)bgf[mi] = *(const float4*)(bgp + mi * 16 + hi * 4);
    #pragma unroll
    for (int ci = 0; ci < 4; ++ci) *(float4*)bff[ci] = *(const float4*)(bf_ + ci * 16 + hi * 4);

    const int li = t & 3, p = t >> 2;
    float4 xv[2][4];
    {   // preload si = 0
        const int s0 = sb * 8;
        #pragma unroll
        for (int k = 0; k < 2; ++k) {
            const float* xp = x + ((size_t)s0 * RDIM + rbase + k * 64 + p) * CDIM + li * 16;
            #pragma unroll
            for (int j = 0; j < 4; ++j) xv[k][j] = *(const float4*)(xp + j * 4);
        }
    }

    for (int si = 0; si < 8; ++si) {
        const int s = sb * 8 + si;
        unsigned short* xb = xs[si & 1];
        // ---- LN (pure xhat) + pack + swizzled LDS store ----
        #pragma unroll
        for (int k = 0; k < 2; ++k) {
            const int row = k * 64 + p;
            float sum = 0.f, sq = 0.f;
            #pragma unroll
            for (int j = 0; j < 4; ++j) {
                sum += xv[k][j].x + xv[k][j].y + xv[k][j].z + xv[k][j].w;
                sq  += xv[k][j].x * xv[k][j].x + xv[k][j].y * xv[k][j].y
                     + xv[k][j].z * xv[k][j].z + xv[k][j].w * xv[k][j].w;
            }
            sum += __shfl_xor(sum, 1, 4); sum += __shfl_xor(sum, 2, 4);
            sq  += __shfl_xor(sq,  1, 4); sq  += __shfl_xor(sq,  2, 4);
            const float mu   = sum * (1.0f / 64.0f);
            const float rstd = rsqrtf(sq * (1.0f / 64.0f) - mu * mu + 1e-5f);
            uint4 w0, w1;
            w0.x = pack2((xv[k][0].x - mu) * rstd, (xv[k][0].y - mu) * rstd);
            w0.y = pack2((xv[k][0].z - mu) * rstd, (xv[k][0].w - mu) * rstd);
            w0.z = pack2((xv[k][1].x - mu) * rstd, (xv[k][1].y - mu) * rstd);
            w0.w = pack2((xv[k][1].z - mu) * rstd, (xv[k][1].w - mu) * rstd);
            w1.x = pack2((xv[k][2].x - mu) * rstd, (xv[k][2].y - mu) * rstd);
            w1.y = pack2((xv[k][2].z - mu) * rstd, (xv[k][2].w - mu) * rstd);
            w1.z = pack2((xv[k][3].x - mu) * rstd, (xv[k][3].y - mu) * rstd);
            w1.w = pack2((xv[k][3].z - mu) * rstd, (xv[k][3].w - mu) * rstd);
            *(uint4*)&xb[row * 64 + (((2 * li)     ^ (row & 7)) << 3)] = w0;
            *(uint4*)&xb[row * 64 + (((2 * li + 1) ^ (row & 7)) << 3)] = w1;
        }
        // ---- prefetch next tile: stays in flight across the barrier ----
        if (si < 7) {
            const int sn = s + 1;
            #pragma unroll
            for (int k = 0; k < 2; ++k) {
                const float* xp = x + ((size_t)sn * RDIM + rbase + k * 64 + p) * CDIM + li * 16;
                #pragma unroll
                for (int j = 0; j < 4; ++j) xv[k][j] = *(const float4*)(xp + j * 4);
            }
        }
        asm volatile("s_waitcnt lgkmcnt(0)" ::: "memory");   // LDS writes visible; vmcnt NOT drained
        __builtin_amdgcn_s_barrier();
        asm volatile("" ::: "memory");

        // ---- GEMM1: z^T = Wg'^T @ xhat^T ----
        f32x4 acc1[4][2];
        #pragma unroll
        for (int mi = 0; mi < 4; ++mi) { acc1[mi][0] = 0; acc1[mi][1] = 0; }
        #pragma unroll
        for (int kst = 0; kst < 2; ++kst) {
            const int swz = (((kst * 4 + hi) ^ (l15 & 7)) << 3);
            const s16x8 bfr0 = *(const s16x8*)&xb[(wv * 32 + l15) * 64 + swz];
            const s16x8 bfr1 = *(const s16x8*)&xb[(wv * 32 + 16 + l15) * 64 + swz];
            #pragma unroll
            for (int mi = 0; mi < 4; ++mi) {
                const s16x8 afr = *(const s16x8*)&wg[(mi * 16 + l15) * 64 + swz];
                acc1[mi][0] = MFMA(afr, bfr0, acc1[mi][0]);
                acc1[mi][1] = MFMA(afr, bfr1, acc1[mi][1]);
            }
        }
        // ---- epilogue in registers: t = sigmoid(z + bg') * o, split-bf16 (hi+lo) ----
        s16x8 a2h[2][2], a2l[2][2];
        #pragma unroll
        for (int ni = 0; ni < 2; ++ni) {
            #pragma unroll
            for (int mi = 0; mi < 4; ++mi) {
                #pragma unroll
                for (int rg = 0; rg < 4; ++rg) {
                    const int slot = ni * 16 + mi * 4 + rg;
                    const float z = acc1[mi][ni][rg] + bgf[mi][rg];
                    const float tv = of32[slot] / (1.0f + __expf(-z));
                    const unsigned short hb = f2bf(tv);
                    const float lo = tv - bf2f(hb);
                    a2h[ni][mi >> 1][((mi & 1) << 2) + rg] = (short)hb;
                    a2l[ni][mi >> 1][((mi & 1) << 2) + rg] = (short)f2bf(lo);
                }
            }
        }
        // ---- GEMM2 (swapped operands, hi+lo compensated): D[cout][row] ----
        f32x4 acc2[2][4];
        #pragma unroll
        for (int ni = 0; ni < 2; ++ni)
            #pragma unroll
            for (int ci = 0; ci < 4; ++ci) acc2[ni][ci] = 0;
        #pragma unroll
        for (int kst = 0; kst < 2; ++kst) {
            const int swz = (((kst * 4 + hi) ^ (l15 & 7)) << 3);
            #pragma unroll
            for (int ci = 0; ci < 4; ++ci) {
                const s16x8 wffr = *(const s16x8*)&wf[(ci * 16 + l15) * 64 + swz];
                acc2[0][ci] = MFMA(wffr, a2h[0][kst], acc2[0][ci]);
                acc2[0][ci] = MFMA(wffr, a2l[0][kst], acc2[0][ci]);
                acc2[1][ci] = MFMA(wffr, a2h[1][kst], acc2[1][ci]);
                acc2[1][ci] = MFMA(wffr, a2l[1][kst], acc2[1][ci]);
            }
        }
        // ---- vectorized stores: float4 per (ni, ci) ----
        #pragma unroll
        for (int ni = 0; ni < 2; ++ni) {
            float* op = out + ((size_t)s * RDIM + rbase + wv * 32 + ni * 16 + l15) * 64 + hi * 4;
            #pragma unroll
            for (int ci = 0; ci < 4; ++ci) {
                float4 res;
                res.x = acc2[ni][ci][0] + bff[ci][0];
                res.y = acc2[ni][ci][1] + bff[ci][1];
                res.z = acc2[ni][ci][2] + bff[ci][2];
                res.w = acc2[ni][ci][3] + bff[ci][3];
                *(float4*)(op + ci * 16) = res;
            }
        }
    }
}

extern "C" void kernel_launch(void* const* d_in, const int* in_sizes, int n_in,
                              void* d_out, int out_size, void* d_ws, size_t ws_size,
                              hipStream_t stream)
{
    const float* x   = (const float*)d_in[0];
    const float* lnw = (const float*)d_in[1];
    const float* lnb = (const float*)d_in[2];
    const float* Wq  = (const float*)d_in[3];
    const float* Wk  = (const float*)d_in[4];
    const float* Wv  = (const float*)d_in[5];
    const float* Wg  = (const float*)d_in[6];
    const float* bg  = (const float*)d_in[7];
    const float* Wf  = (const float*)d_in[8];
    const float* bf  = (const float*)d_in[9];

    char* ws = (char*)d_ws;
    float*          qpart  = (float*)ws;                        // 32*384*64 f32      (3145728 B)
    unsigned short* kv     = (unsigned short*)(ws + 3145728);   // 384*2048*16 bf16   (25165824 B)
    float*          num    = (float*)(ws + 28311552);           // 2*384*64 f32       (196608 B)
    float*          den    = (float*)(ws + 28508160);           // 2*384*8 f32        (24576 B)
    float*          ofimg  = (float*)(ws + 28532736);           // 3*256*32 f32       (98304 B)
    unsigned short* wkvt   = (unsigned short*)(ws + 28631040);  // 16*64 bf16         (2048 B)
    unsigned short* wgt    = (unsigned short*)(ws + 28633088);  // 64*64 bf16         (8192 B)
    unsigned short* wfp    = (unsigned short*)(ws + 28641280);  // 64*64 bf16         (8192 B)
    float*          kvbias = (float*)(ws + 28649472);           // 16 f32             (64 B)
    float*          bgp    = (float*)(ws + 28649536);           // 64 f32             (256 B)

    float* outp = (float*)d_out;

    k_prep<<<3, 256, 0, stream>>>(Wk, Wv, Wg, Wf, lnw, lnb, bg, wkvt, wgt, wfp, kvbias, bgp);
    k_phase1<<<768, 256, 0, stream>>>(x, wkvt, qpart, kv);
    k_phase2a<<<768, 256, 0, stream>>>(qpart, Wq, lnw, lnb, kvbias, kv, num, den);
    k_phase2b<<<96, 256, 0, stream>>>(num, den, kvbias, ofimg);
    k_phase3<<<768, 256, 0, stream>>>(x, wgt, wfp, bgp, bf, ofimg, outp);
}

// Round 12
// 171.816 us; speedup vs baseline: 1.1450x; 1.1450x over previous
//
#include <hip/hip_runtime.h>

#define SEQ  2048
#define RDIM 384
#define CDIM 64

typedef __attribute__((ext_vector_type(8))) short s16x8;
typedef __attribute__((ext_vector_type(4))) float f32x4;
#define MFMA(a,b,c) __builtin_amdgcn_mfma_f32_16x16x32_bf16(a,b,c,0,0,0)

__device__ __forceinline__ unsigned short f2bf(float x) {
    union { float f; unsigned u; } a; a.f = x;
    unsigned r = a.u + 0x7fffu + ((a.u >> 16) & 1u);
    return (unsigned short)(r >> 16);
}
__device__ __forceinline__ unsigned pack2(float lo, float hi) {
    return (unsigned)f2bf(lo) | ((unsigned)f2bf(hi) << 16);
}
__device__ __forceinline__ float bf2f(unsigned u16) {
    union { unsigned u; float f; } a; a.u = u16 << 16; return a.f;
}
__device__ __forceinline__ float uaf(unsigned u) {
    union { unsigned u; float f; } a; a.u = u; return a.f;
}

// element offset of (row, k) in a [rows][64] bf16 tile, 8-elem-group XOR swizzle
#define SWZ(row,k) ((row)*64 + (((((k)>>3) ^ ((row)&7)))<<3) + ((k)&7))

// ---------------- prep: LN-folded transposed/permuted bf16 weights ----------------
__global__ __launch_bounds__(256) void k_prep(
    const float* __restrict__ Wk, const float* __restrict__ Wv,
    const float* __restrict__ Wg, const float* __restrict__ Wf,
    const float* __restrict__ lnw, const float* __restrict__ lnb,
    const float* __restrict__ bg,
    unsigned short* __restrict__ wkvt, unsigned short* __restrict__ wgt,
    unsigned short* __restrict__ wfp, float* __restrict__ kvbias,
    float* __restrict__ bgp)
{
    const int t = threadIdx.x, b = blockIdx.x;
    if (b == 0) {
        for (int idx = t; idx < 16 * 64; idx += 256) {
            const int kc = idx >> 6, k = idx & 63;
            const float v = lnw[k] * ((kc < 8) ? Wk[k * 8 + kc] : Wv[k * 8 + (kc - 8)]);
            wkvt[SWZ(kc, k)] = f2bf(v);
        }
        if (t < 16) {
            float a = 0.f;
            for (int k = 0; k < 64; k++)
                a += lnb[k] * ((t < 8) ? Wk[k * 8 + t] : Wv[k * 8 + (t - 8)]);
            kvbias[t] = a;
        }
    } else if (b == 1) {
        for (int idx = t; idx < 64 * 64; idx += 256) {
            const int col = idx >> 6, k = idx & 63;
            wgt[SWZ(col, k)] = f2bf(lnw[k] * Wg[k * 64 + col]);
        }
        if (t < 64) {
            float a = bg[t];
            for (int k = 0; k < 64; k++) a += lnb[k] * Wg[k * 64 + t];
            bgp[t] = a;
        }
    } else {
        for (int idx = t; idx < 64 * 64; idx += 256) {
            const int cout = idx >> 6, p = idx & 63;
            const int kst = p >> 5, h = (p >> 3) & 3, rr = p & 7;
            const int j = kst * 32 + (rr < 4 ? 4 * h + rr : 16 + 4 * h + (rr - 4));
            wfp[SWZ(cout, p)] = f2bf(Wf[j * 64 + cout]);
        }
    }
}

// ---------------- Phase 1: LN(xhat) + q_avg partials + kv projection (MFMA) ----------------
__global__ __launch_bounds__(256) void k_phase1(
    const float* __restrict__ x, const unsigned short* __restrict__ wkvt,
    float* __restrict__ qpart, unsigned short* __restrict__ kv)
{
    __shared__ __align__(16) unsigned short xs[128 * 64];   // swizzled bf16 xhat sub-tile
    __shared__ __align__(16) unsigned short wkv[16 * 64];   // pre-swizzled LN-folded Wkv^T
    const int t = threadIdx.x;
    ((unsigned*)wkv)[t]       = ((const unsigned*)wkvt)[t];
    ((unsigned*)wkv)[t + 256] = ((const unsigned*)wkvt)[t + 256];

    const int rtile  = blockIdx.x % 24;
    const int schunk = blockIdx.x / 24;
    const int g  = t >> 4;      // row group (fixed r)
    const int c4 = t & 15;      // float4 column
    const int r = rtile * 16 + g;
    const int wv = t >> 6, lane = t & 63, hi = lane >> 4, l15 = lane & 15;

    float qs0 = 0.f, qs1 = 0.f, qs2 = 0.f, qs3 = 0.f;
    for (int sub = 0; sub < 8; ++sub) {
        __syncthreads();   // xs free (iter0: wkv staged)
        #pragma unroll
        for (int it = 0; it < 8; ++it) {
            const int row = it * 16 + g;
            const int s = schunk * 64 + sub * 8 + it;
            const float4 xv = *(const float4*)(x + ((size_t)s * RDIM + r) * CDIM + (c4 << 2));
            float sum = xv.x + xv.y + xv.z + xv.w;
            float sq  = xv.x * xv.x + xv.y * xv.y + xv.z * xv.z + xv.w * xv.w;
            #pragma unroll
            for (int m = 1; m < 16; m <<= 1) {
                sum += __shfl_xor(sum, m, 16);
                sq  += __shfl_xor(sq,  m, 16);
            }
            const float mu   = sum * (1.0f / 64.0f);
            const float rstd = rsqrtf(sq * (1.0f / 64.0f) - mu * mu + 1e-5f);
            const float xn0 = (xv.x - mu) * rstd;
            const float xn1 = (xv.y - mu) * rstd;
            const float xn2 = (xv.z - mu) * rstd;
            const float xn3 = (xv.w - mu) * rstd;
            qs0 += xn0; qs1 += xn1; qs2 += xn2; qs3 += xn3;
            ushort4 pk; pk.x = f2bf(xn0); pk.y = f2bf(xn1); pk.z = f2bf(xn2); pk.w = f2bf(xn3);
            *(ushort4*)&xs[row * 64 + ((((c4 >> 1) ^ (row & 7)) << 3) | ((c4 & 1) << 2))] = pk;
        }
        __syncthreads();
        // kv^T = Wkv'^T @ xhat^T : per wave 32 rows, 4 MFMA
        f32x4 acc0 = 0, acc1 = 0;
        #pragma unroll
        for (int kst = 0; kst < 2; ++kst) {
            const int kg = (kst * 4 + hi);
            const s16x8 a = *(const s16x8*)&wkv[l15 * 64 + ((kg ^ (l15 & 7)) << 3)];
            const int row0 = wv * 32 + l15;
            const s16x8 b0 = *(const s16x8*)&xs[row0 * 64 + ((kg ^ (l15 & 7)) << 3)];
            const s16x8 b1 = *(const s16x8*)&xs[(row0 + 16) * 64 + ((kg ^ (l15 & 7)) << 3)];
            acc0 = MFMA(a, b0, acc0);
            acc1 = MFMA(a, b1, acc1);
        }
        #pragma unroll
        for (int ni = 0; ni < 2; ++ni) {
            const f32x4 av = ni ? acc1 : acc0;
            const int srow = schunk * 64 + sub * 8 + 2 * wv + ni;
            const int rrow = rtile * 16 + l15;
            ushort4 pk; pk.x = f2bf(av[0]); pk.y = f2bf(av[1]); pk.z = f2bf(av[2]); pk.w = f2bf(av[3]);
            *(ushort4*)(kv + ((size_t)rrow * SEQ + srow) * 16 + (hi << 2)) = pk;
        }
    }
    float4 q4; q4.x = qs0; q4.y = qs1; q4.z = qs2; q4.w = qs3;
    *(float4*)(qpart + ((size_t)schunk * RDIM + r) * CDIM + (c4 << 2)) = q4;
}

// ---------------- Phase 2a: q + logits(no-max) + partial den/num per s-half ----------------
__global__ __launch_bounds__(256) void k_phase2a(
    const float* __restrict__ qpart, const float* __restrict__ Wq,
    const float* __restrict__ lnw, const float* __restrict__ lnb,
    const float* __restrict__ kvbias, const unsigned short* __restrict__ kv,
    float* __restrict__ num, float* __restrict__ den)
{
    __shared__ float qa[64];
    __shared__ float ql[64];
    __shared__ float lbias[8];
    __shared__ float hredd[4][8];
    __shared__ float wred[4][64];
    const int t = threadIdx.x;
    const int r = blockIdx.x >> 1;
    const int half = blockIdx.x & 1;
    if (t < 64) {
        float ssum = 0.f;
        #pragma unroll
        for (int ch = 0; ch < 32; ch++) ssum += qpart[(size_t)ch * (RDIM * CDIM) + r * 64 + t];
        qa[t] = ssum;
    }
    __syncthreads();
    if (t < 64) {
        float a = 0.f;
        for (int i = 0; i < 64; i++)
            a += (qa[i] * (1.0f / 2048.0f) * lnw[i] + lnb[i]) * Wq[i * 64 + t];
        ql[t] = a * 0.35355339059327373f;
    }
    __syncthreads();
    if (t < 8) {
        float a = 0.f;
        #pragma unroll
        for (int c = 0; c < 8; c++) a += ql[t * 8 + c] * kvbias[c];
        lbias[t] = a;
    }
    __syncthreads();

    const unsigned short* kvr = kv + (size_t)r * (SEQ * 16);
    float acc[64];
    float pd[8];
    #pragma unroll
    for (int j = 0; j < 64; j++) acc[j] = 0.f;
    #pragma unroll
    for (int h = 0; h < 8; h++) pd[h] = 0.f;

    #pragma unroll
    for (int i = 0; i < 4; i++) {
        const int s = half * 1024 + i * 256 + t;
        const uint4 ku = *(const uint4*)(kvr + (size_t)s * 16);
        const uint4 vu = *(const uint4*)(kvr + (size_t)s * 16 + 8);
        float kf[8], vf[8];
        kf[0] = bf2f(ku.x & 0xffff); kf[1] = bf2f(ku.x >> 16);
        kf[2] = bf2f(ku.y & 0xffff); kf[3] = bf2f(ku.y >> 16);
        kf[4] = bf2f(ku.z & 0xffff); kf[5] = bf2f(ku.z >> 16);
        kf[6] = bf2f(ku.w & 0xffff); kf[7] = bf2f(ku.w >> 16);
        vf[0] = bf2f(vu.x & 0xffff); vf[1] = bf2f(vu.x >> 16);
        vf[2] = bf2f(vu.y & 0xffff); vf[3] = bf2f(vu.y >> 16);
        vf[4] = bf2f(vu.z & 0xffff); vf[5] = bf2f(vu.z >> 16);
        vf[6] = bf2f(vu.w & 0xffff); vf[7] = bf2f(vu.w >> 16);
        #pragma unroll
        for (int h = 0; h < 8; h++) {
            float a = lbias[h];
            #pragma unroll
            for (int c = 0; c < 8; c++) a += ql[h * 8 + c] * kf[c];
            const float e = __expf(a);   // |logit| << 1, no max needed
            pd[h] += e;
            #pragma unroll
            for (int c = 0; c < 8; c++) acc[h * 8 + c] += e * vf[c];
        }
    }
    #pragma unroll
    for (int m = 1; m < 64; m <<= 1) {
        #pragma unroll
        for (int j = 0; j < 64; j++) acc[j] += __shfl_xor(acc[j], m, 64);
        #pragma unroll
        for (int h = 0; h < 8; h++) pd[h] += __shfl_xor(pd[h], m, 64);
    }
    const int wvi = t >> 6, lane = t & 63;
    if (lane == 0) {
        #pragma unroll
        for (int j = 0; j < 64; j++) wred[wvi][j] = acc[j];
        #pragma unroll
        for (int h = 0; h < 8; h++) hredd[wvi][h] = pd[h];
    }
    __syncthreads();
    if (t < 64)
        num[(size_t)(half * RDIM + r) * 64 + t] = wred[0][t] + wred[1][t] + wred[2][t] + wred[3][t];
    if (t < 8)
        den[(size_t)(half * RDIM + r) * 8 + t] = hredd[0][t] + hredd[1][t] + hredd[2][t] + hredd[3][t];
}

// ---------------- Phase 2b: merge halves + pack o into phase3 fragment image ----------------
__global__ __launch_bounds__(256) void k_phase2b(
    const float* __restrict__ num, const float* __restrict__ den,
    const float* __restrict__ kvbias, unsigned short* __restrict__ ofimg)
{
    const int idx = blockIdx.x * 256 + threadIdx.x;   // 0..24575
    const int r = idx >> 6, c = idx & 63;
    const float n = num[idx] + num[RDIM * 64 + idx];
    const float d = den[r * 8 + (c >> 3)] + den[(RDIM + r) * 8 + (c >> 3)];
    const float o = n / d + kvbias[8 + (c & 7)];
    const int rt = r >> 7, row = r & 127;
    const int wv = row >> 5, ni = (row >> 4) & 1, l15 = row & 15;
    const int mi = c >> 4, hi = (c >> 2) & 3, rg = c & 3;
    const int tt = wv * 64 + hi * 16 + l15;
    const int slot = ni * 16 + mi * 4 + rg;
    ofimg[((rt * 256 + tt) << 5) + slot] = f2bf(o);
}

// ---------------- Phase 3: LN + gate GEMM -> reg epilogue -> out GEMM (pipelined) ----------------
__global__ __launch_bounds__(256, 3) void k_phase3(
    const float* __restrict__ x,
    const unsigned short* __restrict__ wgt, const unsigned short* __restrict__ wfp,
    const float* __restrict__ bgp, const float* __restrict__ bf_,
    const unsigned short* __restrict__ ofimg, float* __restrict__ out)
{
    __shared__ __align__(16) unsigned short xs[2][128 * 64];  // dbuf swizzled bf16 xhat
    __shared__ __align__(16) unsigned short wg[64 * 64];      // pre-swizzled LN-folded Wg^T
    __shared__ __align__(16) unsigned short wf[64 * 64];      // pre-swizzled+permuted Wf
    const int t = threadIdx.x;
    const int rt = blockIdx.x % 3;
    const int sb = blockIdx.x / 3;
    const int rbase = rt * 128;

    #pragma unroll
    for (int i = 0; i < 8; ++i) ((unsigned*)wg)[t + i * 256] = ((const unsigned*)wgt)[t + i * 256];
    #pragma unroll
    for (int i = 0; i < 8; ++i) ((unsigned*)wf)[t + i * 256] = ((const unsigned*)wfp)[t + i * 256];

    const int wv = t >> 6, lane = t & 63, hi = lane >> 4, l15 = lane & 15;

    unsigned opk[16];   // o fragments, packed bf16 pairs (slot 2i | 2i+1)
    {
        const unsigned* osrc = (const unsigned*)ofimg + (size_t)(rt * 256 + t) * 16;
        #pragma unroll
        for (int i = 0; i < 16; ++i) opk[i] = osrc[i];
    }
    float bgf[4][4], bff[4][4];
    #pragma unroll
    for (int mi = 0; mi < 4; ++mi) *(float4*)bgf[mi] = *(const float4*)(bgp + mi * 16 + hi * 4);
    #pragma unroll
    for (int ci = 0; ci < 4; ++ci) *(float4*)bff[ci] = *(const float4*)(bf_ + ci * 16 + hi * 4);

    const int li = t & 3, p = t >> 2;
    float4 xv[2][4];
    {   // preload si = 0
        const int s0 = sb * 8;
        #pragma unroll
        for (int k = 0; k < 2; ++k) {
            const float* xp = x + ((size_t)s0 * RDIM + rbase + k * 64 + p) * CDIM + li * 16;
            #pragma unroll
            for (int j = 0; j < 4; ++j) xv[k][j] = *(const float4*)(xp + j * 4);
        }
    }

    for (int si = 0; si < 8; ++si) {
        const int s = sb * 8 + si;
        unsigned short* xb = xs[si & 1];
        // ---- LN (pure xhat) + pack + swizzled LDS store ----
        #pragma unroll
        for (int k = 0; k < 2; ++k) {
            const int row = k * 64 + p;
            float sum = 0.f, sq = 0.f;
            #pragma unroll
            for (int j = 0; j < 4; ++j) {
                sum += xv[k][j].x + xv[k][j].y + xv[k][j].z + xv[k][j].w;
                sq  += xv[k][j].x * xv[k][j].x + xv[k][j].y * xv[k][j].y
                     + xv[k][j].z * xv[k][j].z + xv[k][j].w * xv[k][j].w;
            }
            sum += __shfl_xor(sum, 1, 4); sum += __shfl_xor(sum, 2, 4);
            sq  += __shfl_xor(sq,  1, 4); sq  += __shfl_xor(sq,  2, 4);
            const float mu   = sum * (1.0f / 64.0f);
            const float rstd = rsqrtf(sq * (1.0f / 64.0f) - mu * mu + 1e-5f);
            uint4 w0, w1;
            w0.x = pack2((xv[k][0].x - mu) * rstd, (xv[k][0].y - mu) * rstd);
            w0.y = pack2((xv[k][0].z - mu) * rstd, (xv[k][0].w - mu) * rstd);
            w0.z = pack2((xv[k][1].x - mu) * rstd, (xv[k][1].y - mu) * rstd);
            w0.w = pack2((xv[k][1].z - mu) * rstd, (xv[k][1].w - mu) * rstd);
            w1.x = pack2((xv[k][2].x - mu) * rstd, (xv[k][2].y - mu) * rstd);
            w1.y = pack2((xv[k][2].z - mu) * rstd, (xv[k][2].w - mu) * rstd);
            w1.z = pack2((xv[k][3].x - mu) * rstd, (xv[k][3].y - mu) * rstd);
            w1.w = pack2((xv[k][3].z - mu) * rstd, (xv[k][3].w - mu) * rstd);
            *(uint4*)&xb[row * 64 + (((2 * li)     ^ (row & 7)) << 3)] = w0;
            *(uint4*)&xb[row * 64 + (((2 * li + 1) ^ (row & 7)) << 3)] = w1;
        }
        // ---- prefetch next tile: stays in flight across the barrier ----
        if (si < 7) {
            const int sn = s + 1;
            #pragma unroll
            for (int k = 0; k < 2; ++k) {
                const float* xp = x + ((size_t)sn * RDIM + rbase + k * 64 + p) * CDIM + li * 16;
                #pragma unroll
                for (int j = 0; j < 4; ++j) xv[k][j] = *(const float4*)(xp + j * 4);
            }
        }
        asm volatile("s_waitcnt lgkmcnt(0)" ::: "memory");   // LDS writes visible; vmcnt NOT drained
        __builtin_amdgcn_s_barrier();
        asm volatile("" ::: "memory");

        // ---- GEMM1: z^T = Wg'^T @ xhat^T ----
        f32x4 acc1[4][2];
        #pragma unroll
        for (int mi = 0; mi < 4; ++mi) { acc1[mi][0] = 0; acc1[mi][1] = 0; }
        #pragma unroll
        for (int kst = 0; kst < 2; ++kst) {
            const int swz = (((kst * 4 + hi) ^ (l15 & 7)) << 3);
            const s16x8 bfr0 = *(const s16x8*)&xb[(wv * 32 + l15) * 64 + swz];
            const s16x8 bfr1 = *(const s16x8*)&xb[(wv * 32 + 16 + l15) * 64 + swz];
            #pragma unroll
            for (int mi = 0; mi < 4; ++mi) {
                const s16x8 afr = *(const s16x8*)&wg[(mi * 16 + l15) * 64 + swz];
                acc1[mi][0] = MFMA(afr, bfr0, acc1[mi][0]);
                acc1[mi][1] = MFMA(afr, bfr1, acc1[mi][1]);
            }
        }
        // ---- epilogue in registers: t = sigmoid(z + bg') * o ----
        s16x8 a2[2][2];
        #pragma unroll
        for (int ni = 0; ni < 2; ++ni) {
            #pragma unroll
            for (int mi = 0; mi < 4; ++mi) {
                #pragma unroll
                for (int rg = 0; rg < 4; ++rg) {
                    const int slot = ni * 16 + mi * 4 + rg;
                    const unsigned u = opk[slot >> 1];
                    const float of = uaf((slot & 1) ? (u & 0xffff0000u) : (u << 16));
                    const float z = acc1[mi][ni][rg] + bgf[mi][rg];
                    const float tv = of / (1.0f + __expf(-z));
                    a2[ni][mi >> 1][((mi & 1) << 2) + rg] = (short)f2bf(tv);
                }
            }
        }
        // ---- GEMM2 (swapped operands): D[cout][row] ----
        f32x4 acc2[2][4];
        #pragma unroll
        for (int ni = 0; ni < 2; ++ni)
            #pragma unroll
            for (int ci = 0; ci < 4; ++ci) acc2[ni][ci] = 0;
        #pragma unroll
        for (int kst = 0; kst < 2; ++kst) {
            const int swz = (((kst * 4 + hi) ^ (l15 & 7)) << 3);
            #pragma unroll
            for (int ci = 0; ci < 4; ++ci) {
                const s16x8 wffr = *(const s16x8*)&wf[(ci * 16 + l15) * 64 + swz];
                acc2[0][ci] = MFMA(wffr, a2[0][kst], acc2[0][ci]);
                acc2[1][ci] = MFMA(wffr, a2[1][kst], acc2[1][ci]);
            }
        }
        // ---- vectorized stores: float4 per (ni, ci) ----
        #pragma unroll
        for (int ni = 0; ni < 2; ++ni) {
            float* op = out + ((size_t)s * RDIM + rbase + wv * 32 + ni * 16 + l15) * 64 + hi * 4;
            #pragma unroll
            for (int ci = 0; ci < 4; ++ci) {
                float4 res;
                res.x = acc2[ni][ci][0] + bff[ci][0];
                res.y = acc2[ni][ci][1] + bff[ci][1];
                res.z = acc2[ni][ci][2] + bff[ci][2];
                res.w = acc2[ni][ci][3] + bff[ci][3];
                *(float4*)(op + ci * 16) = res;
            }
        }
    }
}

extern "C" void kernel_launch(void* const* d_in, const int* in_sizes, int n_in,
                              void* d_out, int out_size, void* d_ws, size_t ws_size,
                              hipStream_t stream)
{
    const float* x   = (const float*)d_in[0];
    const float* lnw = (const float*)d_in[1];
    const float* lnb = (const float*)d_in[2];
    const float* Wq  = (const float*)d_in[3];
    const float* Wk  = (const float*)d_in[4];
    const float* Wv  = (const float*)d_in[5];
    const float* Wg  = (const float*)d_in[6];
    const float* bg  = (const float*)d_in[7];
    const float* Wf  = (const float*)d_in[8];
    const float* bf  = (const float*)d_in[9];

    char* ws = (char*)d_ws;
    float*          qpart  = (float*)ws;                        // 32*384*64 f32      @ 0        (3145728 B)
    unsigned short* kv     = (unsigned short*)(ws + 3145728);   // 384*2048*16 bf16   (25165824 B)
    float*          num    = (float*)(ws + 28311552);           // 2*384*64 f32       (196608 B)
    float*          den    = (float*)(ws + 28508160);           // 2*384*8 f32        (24576 B)
    unsigned short* ofimg  = (unsigned short*)(ws + 28532736);  // 3*256*32 bf16      (49152 B)
    unsigned short* wkvt   = (unsigned short*)(ws + 28581888);  // 16*64 bf16         (2048 B)
    unsigned short* wgt    = (unsigned short*)(ws + 28583936);  // 64*64 bf16         (8192 B)
    unsigned short* wfp    = (unsigned short*)(ws + 28592128);  // 64*64 bf16         (8192 B)
    float*          kvbias = (float*)(ws + 28600320);           // 16 f32             (64 B)
    float*          bgp    = (float*)(ws + 28600384);           // 64 f32             (256 B)

    float* outp = (float*)d_out;

    k_prep<<<3, 256, 0, stream>>>(Wk, Wv, Wg, Wf, lnw, lnb, bg, wkvt, wgt, wfp, kvbias, bgp);
    k_phase1<<<768, 256, 0, stream>>>(x, wkvt, qpart, kv);
    k_phase2a<<<768, 256, 0, stream>>>(qpart, Wq, lnw, lnb, kvbias, kv, num, den);
    k_phase2b<<<96, 256, 0, stream>>>(num, den, kvbias, ofimg);
    k_phase3<<<768, 256, 0, stream>>>(x, wgt, wfp, bgp, bf, ofimg, outp);
}